// Round 18
// baseline (289.435 us; speedup 1.0000x reference)
//
#include <hip/hip_runtime.h>
#include <hip/hip_bf16.h>
#include <stdint.h>

#define CHUNKC 32
#define PRIORC 64
#define POSEC 512
#define PREDC 128
#define NB 2048
#define K1 (CHUNKC*POSEC)   // 16384
#define KS 8                // split-K factor (bf16 partials)
#define KCH (K1/KS)         // 2048
#define NIT (KCH/64)        // 32

typedef __attribute__((ext_vector_type(8))) short bf16x8;
typedef __attribute__((ext_vector_type(8))) unsigned short u16x8;
typedef __attribute__((ext_vector_type(4))) float f32x4;
typedef __attribute__((ext_vector_type(4))) float f4v;

__device__ __forceinline__ unsigned short f2b(float f) {
    union { float f; unsigned int u; } x; x.f = f;
    unsigned int r = x.u + 0x7fffu + ((x.u >> 16) & 1u);
    return (unsigned short)(r >> 16);
}
__device__ __forceinline__ float b2f(unsigned short u) {
    union { unsigned int i; float f; } x; x.i = ((unsigned int)u) << 16; return x.f;
}
__device__ __forceinline__ unsigned short cf(float f) {
    __hip_bfloat16 h = __float2bfloat16(f);
    union { __hip_bfloat16 h; unsigned short u; } x; x.h = h; return x.u;
}

__device__ __forceinline__ void gload_lds16(const void* g, void* l) {
    __builtin_amdgcn_global_load_lds(
        (const __attribute__((address_space(1))) unsigned int*)g,
        (__attribute__((address_space(3))) unsigned int*)l, 16, 0, 0);
}

// ---------------- cvt_w: W1, W2 -> bf16 ----------------
#define W1N4  2097152   // 512*16384/4
#define W2N4  65536     // 512*512/4
__global__ __launch_bounds__(256) void cvt_w_kernel(const float4* __restrict__ W1,
                                                    const float4* __restrict__ W2,
                                                    ushort4* __restrict__ w1b,
                                                    ushort4* __restrict__ w2b) {
    const int64_t n = W1N4 + W2N4;
    const int64_t stride = (int64_t)gridDim.x * blockDim.x;
    for (int64_t i = (int64_t)blockIdx.x * blockDim.x + threadIdx.x; i < n; i += stride) {
        float4 v; ushort4* dst;
        if (i < W1N4) { v = W1[i]; dst = w1b + i; }
        else          { v = W2[i - W1N4]; dst = w2b + (i - W1N4); }
        *dst = make_ushort4(f2b(v.x), f2b(v.y), f2b(v.z), f2b(v.w));
    }
}

// ---------------- GEMM1: bf16 partials of x @ W1^T ----------------
// R14 counted-vmcnt schedule + T14 reg-staged A with dedup'd cvt:
//  - A loaded f32 -> REGS (each elem once), cvt'd ONCE, ds_write'd bf16 (16 KB
//    tiles). A LDS fragment reads halve (8 b128/wave/iter vs 16); cvt VALU -75%.
//  - B staged bf16 via gload_lds (R14-proven path).
// Per iter: issue Areg(it+2) + STAGE_B(it+1) -> vmcnt(8) [drains Areg(it+1),
// B(it)] -> cvt+ds_write A(it+1) -> lgkmcnt(0) -> B1 -> MFMA(it) -> B2.
// Regsets: two NAMED arrays alternated by 2x-unrolled loop (rule #20).
// LDS = A bf16 2x16 KB + B 2x32 KB = 96 KB. grid = 16mt*2nt*8ks = 256.
__global__ __launch_bounds__(512) void gemm1_kernel(const float* __restrict__ init,
                                                    const ushort* __restrict__ w1b,
                                                    ushort* __restrict__ part) {
    __shared__ ushort Ab[2][128][64];   // 2 x 16 KB bf16
    __shared__ ushort Bs[2][256][64];   // 2 x 32 KB bf16
    const int t = threadIdx.x;
    const int l = t & 63, wid = t >> 6;
    const int wr = wid >> 2, wc = wid & 3;
    const int orig = (blockIdx.x & 7) * 32 + (blockIdx.x >> 3);
    const int mt = orig & 15, nt = (orig >> 4) & 1, ks = orig >> 5;

    f32x4 acc[4][4] = {};

    // A reg-staging map: thread covers row agr = t>>2 (4 thr/row), 16 cols at agc.
    const int agr = t >> 2;
    const int agc = (t & 3) * 16;
    const int akey = agr & 7;
    const int as0 = (t & 3) * 2;                    // logical 16B-slot pair base
    const int aw0 = (as0 ^ akey) * 8;               // phys ushort offsets
    const int aw1 = ((as0 + 1) ^ akey) * 8;
    const float* aRow = init + (int64_t)(mt * 128 + agr) * 32768 + 16384 + ks * KCH + agc;

    // B staging (gload_lds, pre-swizzled source)
    const ushort* bG = w1b + (int64_t)(nt * 256) * K1 + ks * KCH;
    const int brow = t >> 3;
    const int bcol = ((t & 7) ^ ((t >> 3) & 7)) * 8;

    const int fr = l & 15, fq = l >> 4;
    const int cx = fr & 7;

    f32x4 ar0[4], ar1[4];                           // two named regsets

    auto AISSUE = [&](f32x4 (&set)[4], int k0) {
#pragma unroll
        for (int i = 0; i < 4; ++i)
            set[i] = *(const f32x4*)(aRow + k0 + i * 4);
    };
    auto STAGE_B = [&](int buf, int k0) {           // 4 gload_lds
#pragma unroll
        for (int i = 0; i < 4; ++i)
            gload_lds16(bG + (int64_t)(i * 64 + brow) * K1 + k0 + bcol,
                        (char*)&Bs[buf][0][0] + i * 8192 + wid * 1024);
    };
    auto CVTWRITE = [&](f32x4 (&set)[4], int buf) {
        u16x8 w0, w1;
#pragma unroll
        for (int j = 0; j < 4; ++j) {
            w0[j] = cf(set[0][j]); w0[j + 4] = cf(set[1][j]);
            w1[j] = cf(set[2][j]); w1[j + 4] = cf(set[3][j]);
        }
        *(u16x8*)&Ab[buf][agr][aw0] = w0;
        *(u16x8*)&Ab[buf][agr][aw1] = w1;
    };
    auto MFMA_PHASE = [&](int cur) {
        __builtin_amdgcn_s_barrier();               // B1: tile cur fully in LDS
        asm volatile("" ::: "memory");
        __builtin_amdgcn_sched_barrier(0);
        __builtin_amdgcn_s_setprio(1);
#pragma unroll
        for (int k2 = 0; k2 < 2; ++k2) {
            const int cs = ((k2 * 4 + fq) ^ cx) * 8;
            bf16x8 a[4], b[4];
#pragma unroll
            for (int m = 0; m < 4; ++m)
                a[m] = *(const bf16x8*)&Ab[cur][wr * 64 + m * 16 + fr][cs];
#pragma unroll
            for (int n = 0; n < 4; ++n)
                b[n] = *(const bf16x8*)&Bs[cur][wc * 64 + n * 16 + fr][cs];
#pragma unroll
            for (int m = 0; m < 4; ++m)
#pragma unroll
                for (int n = 0; n < 4; ++n)
                    acc[m][n] = __builtin_amdgcn_mfma_f32_16x16x32_bf16(a[m], b[n], acc[m][n], 0, 0, 0);
        }
        __builtin_amdgcn_s_setprio(0);
        asm volatile("" ::: "memory");              // pin LDS reads above B2
        __builtin_amdgcn_s_barrier();               // B2: buffers reusable
    };
    // One pipelined iteration; cvtset holds A(it+1), issueset receives A(it+2).
    auto ITER = [&](int it, f32x4 (&cvtset)[4], f32x4 (&issueset)[4]) {
        if (it + 2 < NIT) {
            AISSUE(issueset, (it + 2) * 64);        // +4 (regs)
            STAGE_B((it + 1) & 1, (it + 1) * 64);   // +4 (lds)
            // outstanding: Areg(it+1),B(it),Areg(it+2),B(it+1) = 16 -> drain 8
            asm volatile("s_waitcnt vmcnt(8)" ::: "memory");
            CVTWRITE(cvtset, (it + 1) & 1);         // A(it+1) -> LDS bf16
            asm volatile("s_waitcnt lgkmcnt(0)" ::: "memory");
        } else if (it + 1 < NIT) {
            STAGE_B((it + 1) & 1, (it + 1) * 64);
            // outstanding: Areg(it+1),B(it),B(it+1) = 12 -> drain 8, leave B(it+1)
            asm volatile("s_waitcnt vmcnt(4)" ::: "memory");
            CVTWRITE(cvtset, (it + 1) & 1);
            asm volatile("s_waitcnt lgkmcnt(0)" ::: "memory");
        } else {
            asm volatile("s_waitcnt vmcnt(0)" ::: "memory");
        }
        MFMA_PHASE(it & 1);
    };

    // prologue: A(0)->ar0, A(1)->ar1, B(0); wait A(0); cvt->Ab[0]
    AISSUE(ar0, 0);
    AISSUE(ar1, 64);
    STAGE_B(0, 0);
    asm volatile("s_waitcnt vmcnt(8)" ::: "memory");    // A(0) arrived
    CVTWRITE(ar0, 0);
    // (lgkm drain for these writes happens inside ITER(0) before its barrier)

#pragma unroll 1
    for (int ito = 0; ito < NIT / 2; ++ito) {
        ITER(2 * ito,     ar1, ar0);    // cvt A(2ito+1), issue A(2ito+2)->ar0
        ITER(2 * ito + 1, ar0, ar1);    // cvt A(2ito+2), issue A(2ito+3)->ar1
    }

    ushort* P = part + (int64_t)ks * NB * POSEC;
    const int mbase = mt * 128 + wr * 64, nbase = nt * 256 + wc * 64;
#pragma unroll
    for (int m = 0; m < 4; ++m)
#pragma unroll
        for (int n = 0; n < 4; ++n) {
            int row0 = mbase + m * 16 + fq * 4;
            int col  = nbase + n * 16 + fr;
#pragma unroll
            for (int r = 0; r < 4; ++r)
                P[(int64_t)(row0 + r) * POSEC + col] = f2b(acc[m][n][r]);
        }
}

// ---------------- reduce: A2 = bf16(sum_ks bf16part + b1) ----------------
__global__ __launch_bounds__(256) void reduce_kernel(const ushort* __restrict__ part,
                                                     const float* __restrict__ b1,
                                                     u16x8* __restrict__ A2) {
    const int gid = blockIdx.x * 256 + threadIdx.x;     // 131072 threads, 8 elems each
    const int64_t e0 = (int64_t)gid * 8;
    float s[8] = {};
#pragma unroll
    for (int k = 0; k < KS; ++k) {
        u16x8 p = *(const u16x8*)(part + (int64_t)k * (NB * POSEC) + e0);
#pragma unroll
        for (int j = 0; j < 8; ++j) s[j] += b2f(p[j]);
    }
    const int col = (int)(e0 & 511);
    f4v b0 = *(const f4v*)&b1[col];
    f4v b4 = *(const f4v*)&b1[col + 4];
    u16x8 o;
#pragma unroll
    for (int j = 0; j < 4; ++j) { o[j] = f2b(s[j] + b0[j]); o[j+4] = f2b(s[j+4] + b4[j]); }
    A2[gid] = o;
}

// ---------------- GEMM2: mem = A2 @ W2b^T + b2 (R9-proven, swizzled) ----------------
__global__ __launch_bounds__(256) void gemm2_kernel(const ushort* __restrict__ A2,
                                                    const ushort* __restrict__ w2b,
                                                    const float* __restrict__ b2,
                                                    float* __restrict__ mem) {
    __shared__ ushort As[64][64];
    __shared__ ushort Bs[64][64];
    const int t = threadIdx.x;
    const int l = t & 63, wid = t >> 6;
    const int wr = wid >> 1, wc = wid & 1;
    const int mt = blockIdx.x >> 3, nt = blockIdx.x & 7;

    f32x4 acc[2][2] = {};
    const ushort* aG = A2  + (int64_t)(mt * 64) * POSEC;
    const ushort* bG = w2b + (int64_t)(nt * 64) * POSEC;
    const int srow = t >> 3;
    const int scol = (((t & 7) ^ ((t >> 3) & 7))) * 8;
    const int fr = l & 15, fq = l >> 4;
    const int cx = fr & 7;

    for (int k0 = 0; k0 < POSEC; k0 += 64) {
#pragma unroll
        for (int i = 0; i < 2; ++i) {
            gload_lds16(aG + (int64_t)(i * 32 + srow) * POSEC + k0 + scol,
                        (char*)&As[0][0] + i * 4096 + wid * 1024);
            gload_lds16(bG + (int64_t)(i * 32 + srow) * POSEC + k0 + scol,
                        (char*)&Bs[0][0] + i * 4096 + wid * 1024);
        }
        __syncthreads();
#pragma unroll
        for (int k2 = 0; k2 < 2; ++k2) {
            const int cs = ((k2 * 4 + fq) ^ cx) * 8;
            bf16x8 a[2], b[2];
#pragma unroll
            for (int m = 0; m < 2; ++m)
                a[m] = *(const bf16x8*)&As[wr * 32 + m * 16 + fr][cs];
#pragma unroll
            for (int n = 0; n < 2; ++n)
                b[n] = *(const bf16x8*)&Bs[wc * 32 + n * 16 + fr][cs];
#pragma unroll
            for (int m = 0; m < 2; ++m)
#pragma unroll
                for (int n = 0; n < 2; ++n)
                    acc[m][n] = __builtin_amdgcn_mfma_f32_16x16x32_bf16(a[m], b[n], acc[m][n], 0, 0, 0);
        }
        __syncthreads();
    }

    const int mbase = mt * 64 + wr * 32, nbase = nt * 64 + wc * 32;
#pragma unroll
    for (int m = 0; m < 2; ++m)
#pragma unroll
        for (int n = 0; n < 2; ++n) {
            int row0 = mbase + m * 16 + fq * 4;
            int col  = nbase + n * 16 + fr;
            float bias = b2[col];
#pragma unroll
            for (int r = 0; r < 4; ++r)
                mem[(int64_t)(row0 + r) * POSEC + col] = acc[m][n][r] + bias;
        }
}

// ---------------- score + sigmoid + blend + copy ----------------
__global__ __launch_bounds__(256) void blend_kernel(const float* __restrict__ pred,
                                                    const float* __restrict__ mem,
                                                    float* __restrict__ out) {
    const int b = blockIdx.x;
    const int t = threadIdx.x;
    __shared__ float sm[POSEC];
    __shared__ float sg[CHUNKC];

    sm[t]       = mem[(int64_t)b * POSEC + t];
    sm[t + 256] = mem[(int64_t)b * POSEC + 256 + t];
    __syncthreads();

    const int l = t & 63, wid = t >> 6;
    const float4* sm4 = (const float4*)sm;
    const float4* p4 = (const float4*)pred + (int64_t)b * 16384;
    float4* o4 = (float4*)out + (int64_t)b * 16384;

#pragma unroll
    for (int ci = 0; ci < 8; ++ci) {
        int c = wid * 8 + ci;
        float4 h0 = p4[c * 128 + l * 2];
        float4 h1 = p4[c * 128 + l * 2 + 1];
        float4 m0 = sm4[l * 2];
        float4 m1 = sm4[l * 2 + 1];
        float s = h0.x * m0.x + h0.y * m0.y + h0.z * m0.z + h0.w * m0.w
                + h1.x * m1.x + h1.y * m1.y + h1.z * m1.z + h1.w * m1.w;
#pragma unroll
        for (int o = 32; o; o >>= 1) s += __shfl_xor(s, o);
        if (l == 0) sg[c] = 1.0f / (1.0f + expf(-s));
    }
    __syncthreads();

#pragma unroll
    for (int i = 0; i < 16; ++i) {
        int idx = i * 256 + t;
        int row = idx >> 7, c4 = idx & 127;
        float g = sg[row];
        float4 h = p4[idx];
        float4 m = sm4[c4];
        float4 r;
        r.x = g * h.x + (1.0f - g) * m.x;
        r.y = g * h.y + (1.0f - g) * m.y;
        r.z = g * h.z + (1.0f - g) * m.z;
        r.w = g * h.w + (1.0f - g) * m.w;
        o4[idx] = r;
    }
#pragma unroll
    for (int i = 0; i < 48; ++i) {
        int idx = 4096 + i * 256 + t;
        f4v h = __builtin_nontemporal_load((const f4v*)p4 + idx);
        __builtin_nontemporal_store(h, (f4v*)o4 + idx);
    }
}

// ---------------- launch ----------------

extern "C" void kernel_launch(void* const* d_in, const int* in_sizes, int n_in,
                              void* d_out, int out_size, void* d_ws, size_t ws_size,
                              hipStream_t stream) {
    const float* init = (const float*)d_in[0];
    const float* pred = (const float*)d_in[1];
    const float* W1   = (const float*)d_in[2];
    const float* b1   = (const float*)d_in[3];
    const float* W2   = (const float*)d_in[4];
    const float* b2   = (const float*)d_in[5];
    float* out = (float*)d_out;

    char* ws = (char*)d_ws;
    ushort* w1b  = (ushort*)(ws);                       // 16777216 B
    ushort* w2b  = (ushort*)(ws + 16777216);            //   524288 B
    ushort* part = (ushort*)(ws + 17301504);            // 16777216 B (8 x 2048x512 bf16)
    ushort* A2   = (ushort*)(ws + 34078720);            //  2097152 B
    float*  mem  = (float*) (ws + 36175872);            //  4194304 B
    // total 40,370,176 B

    cvt_w_kernel<<<1024, 256, 0, stream>>>((const float4*)W1, (const float4*)W2,
                                           (ushort4*)w1b, (ushort4*)w2b);
    gemm1_kernel<<<256, 512, 0, stream>>>(init, w1b, part);
    reduce_kernel<<<512, 256, 0, stream>>>(part, b1, (u16x8*)A2);
    gemm2_kernel<<<256, 256, 0, stream>>>(A2, w2b, b2, mem);
    blend_kernel<<<NB, 256, 0, stream>>>(pred, mem, out);
}